// Round 7
// baseline (390.692 us; speedup 1.0000x reference)
//
#include <hip/hip_runtime.h>
#include <math.h>

#define BB 2
#define TT 8
#define NN 512
#define HH 64
#define NC 10
#define NBLK 256

typedef unsigned char uchar;

__device__ __forceinline__ float elu1(float v){ return v > 0.f ? v : expm1f(v); }
__device__ __forceinline__ float sigm(float v){ return 1.f/(1.f+expf(-v)); }

// Hand-rolled grid barrier (sense/generation). bar[0]=arrive, bar[1]=generation.
// All 256 blocks are co-resident by construction (1 block/CU, 52.7KB LDS).
__device__ __forceinline__ void grid_barrier(unsigned* bar){
    __syncthreads();
    if (threadIdx.x == 0){
        __threadfence();   // release our block's writes (agent-scope wb)
        unsigned gen = __hip_atomic_load(&bar[1], __ATOMIC_ACQUIRE, __HIP_MEMORY_SCOPE_AGENT);
        unsigned a = __hip_atomic_fetch_add(&bar[0], 1u, __ATOMIC_ACQ_REL, __HIP_MEMORY_SCOPE_AGENT);
        if (a == NBLK - 1u){
            __hip_atomic_store(&bar[0], 0u, __ATOMIC_RELAXED, __HIP_MEMORY_SCOPE_AGENT);
            __hip_atomic_fetch_add(&bar[1], 1u, __ATOMIC_RELEASE, __HIP_MEMORY_SCOPE_AGENT);
        } else {
            while (__hip_atomic_load(&bar[1], __ATOMIC_ACQUIRE, __HIP_MEMORY_SCOPE_AGENT) == gen)
                __builtin_amdgcn_s_sleep(8);
        }
        __threadfence();   // acquire: invalidate caches before reading others' data
    }
    __syncthreads();
}

struct Prm {
    const float *x_seq, *sadj, *dW, *lamp;
    const float *g1_Wl, *g1_Wr, *g1_att, *g1_b;
    const float *g2_Wl, *g2_Wr, *g2_att, *g2_b;
    const float *Wih0, *bih0, *bhh0;
    const float *bih1, *bhh1;
    const float *attnW, *attnb, *W1, *b1, *lng, *lnb, *W2, *b2;
    uchar *M0, *M1;
    float *WT4;
    float *xl2, *xr2, *ui, *vj, *meanPart;
    unsigned *bar;
    float *out;
};

// ---------------- k_init: WT4 quad-transpose, gts, zero barrier ----------------
__global__ __launch_bounds__(256) void k_init(
    const float* __restrict__ Whh0, const float* __restrict__ Wih1,
    const float* __restrict__ Whh1, const float* __restrict__ lamp,
    float4* __restrict__ WT4, unsigned* __restrict__ bar, float* __restrict__ out)
{
    int idx = blockIdx.x*256 + threadIdx.x;    // 48*256 = 12288 = 3*4096
    if (blockIdx.x == 0){
        if (threadIdx.x < 2) bar[threadIdx.x] = 0u;
        if (threadIdx.x >= 32 && threadIdx.x < 32 + TT){
            int t = threadIdx.x - 32;
            float lam = fmaxf(lamp[0], 0.01f);
            out[BB*NC + t] = expf(-lam*(float)t);          // gts
        }
    }
    int m = idx >> 12, r = idx & 4095;
    int gg = r >> 6, k = r & 63;
    const float* W = (m == 0) ? Whh0 : (m == 1) ? Wih1 : Whh1;
    float4 o;
    o.x = W[k*192 + gg];
    o.y = W[k*192 + 64 + gg];
    o.z = W[k*192 + 128 + gg];
    o.w = 0.f;
    WT4[idx] = o;
}

#define SMEM_BYTES 52736

__global__ __launch_bounds__(256, 1) void mega(Prm p)
{
    __shared__ __align__(16) char smem[SMEM_BYTES];
    int blk = blockIdx.x;
    int tid = threadIdx.x;

    // ================= P0: masks =================
    if (blk < 64){
        float (*tr)[65] = (float(*)[65])smem;
        int i0 = (blk >> 3)*64, j0 = (blk & 7)*64;
        #pragma unroll
        for (int q = 0; q < 4; ++q){
            int r = (tid >> 4) + 16*q, c4 = tid & 15;
            float4 v = *(const float4*)&p.dW[(size_t)(j0+r)*NN + i0 + 4*c4];
            tr[r][4*c4+0] = v.x; tr[r][4*c4+1] = v.y;
            tr[r][4*c4+2] = v.z; tr[r][4*c4+3] = v.w;
        }
        __syncthreads();
        #pragma unroll
        for (int q = 0; q < 4; ++q){
            int row = (tid >> 4) + 16*q, c4 = tid & 15;
            int i = i0 + row, j = j0 + 4*c4;
            float4 d  = *(const float4*)&p.dW[(size_t)i*NN + j];
            float4 sa = *(const float4*)&p.sadj[(size_t)i*NN + j];
            uchar4 m0, m1;
            float dd0 = d.x + tr[4*c4+0][row];
            float dd1 = d.y + tr[4*c4+1][row];
            float dd2 = d.z + tr[4*c4+2][row];
            float dd3 = d.w + tr[4*c4+3][row];
            m0.x = (sa.x > 0.f) || (i == j+0);
            m0.y = (sa.y > 0.f) || (i == j+1);
            m0.z = (sa.z > 0.f) || (i == j+2);
            m0.w = (sa.w > 0.f) || (i == j+3);
            m1.x = m0.x || (dd0 > 0.f);
            m1.y = m0.y || (dd1 > 0.f);
            m1.z = m0.z || (dd2 > 0.f);
            m1.w = m0.w || (dd3 > 0.f);
            *(uchar4*)&p.M0[(size_t)i*NN + j] = m0;
            *(uchar4*)&p.M1[(size_t)i*NN + j] = m1;
        }
    }
    grid_barrier(p.bar);

    // ================= P1: GAT1 + lin2 (32 rows / block) =================
    {
        float* Wl2s = (float*)smem;               // 16384 B
        float* Wr2s = (float*)(smem + 16384);     // 16384 B
        float* x_s  = (float*)(smem + 32768);     // 2048 B
        float (*h_s)[64] = (float(*)[64])(smem + 34816);  // 1024 B
        float (*S_s)[4]  = (float(*)[4]) (smem + 35840);  // 64 B
        float* AB_s = (float*)(smem + 35904);     // 32 B
        int bt = blk >> 4, ig = blk & 15;
        int t = bt % TT;
        #pragma unroll
        for (int q = 0; q < 4; ++q){
            int idx = q*256 + tid;
            ((float4*)Wl2s)[idx] = ((const float4*)p.g2_Wl)[idx];
            ((float4*)Wr2s)[idx] = ((const float4*)p.g2_Wr)[idx];
        }
        ((float2*)x_s)[tid] = ((const float2*)(p.x_seq + bt*NN))[tid];
        if (tid < 8){
            int h = tid & 3;
            const float* W = (tid < 4) ? p.g1_Wr : p.g1_Wl;
            float s = 0.f;
            for (int c = 0; c < 16; ++c) s += p.g1_att[h*16+c]*W[h*16+c];
            AB_s[tid] = s;
        }
        __syncthreads();
        const uchar* M = t ? p.M1 : p.M0;
        int il = tid >> 6, jl = tid & 63;
        float xj[8];
        #pragma unroll
        for (int jj = 0; jj < 8; ++jj) xj[jj] = x_s[jj*64 + jl];
        for (int s = 0; s < 8; ++s){
            int i = ig*32 + s*4 + il;
            float xi = x_s[i];
            const uchar* Mrow = M + (size_t)i*NN;
            float msk[8];
            #pragma unroll
            for (int jj = 0; jj < 8; ++jj) msk[jj] = Mrow[jj*64 + jl] ? 1.f : 0.f;
            float sw[4] = {0,0,0,0}, swx[4] = {0,0,0,0};
            for (int h = 0; h < 4; ++h){
                float acc[8] = {0,0,0,0,0,0,0,0};
                #pragma unroll
                for (int c = 0; c < 16; ++c){
                    int hc = h*16 + c;
                    float wl = p.g1_Wl[hc];
                    float q  = 0.4f * p.g1_att[hc];
                    float pr = xi * p.g1_Wr[hc];
                    #pragma unroll
                    for (int jj = 0; jj < 8; ++jj){
                        float sv = fmaf(xj[jj], wl, pr);
                        acc[jj] = fmaf(q, fabsf(sv), acc[jj]);
                    }
                }
                float lin = 0.6f * xi * AB_s[h];
                float al6 = 0.6f * AB_s[4+h];
                #pragma unroll
                for (int jj = 0; jj < 8; ++jj){
                    float e = acc[jj] + fmaf(al6, xj[jj], lin);
                    float w = msk[jj] * __expf(e);
                    sw[h] += w;
                    swx[h] = fmaf(w, xj[jj], swx[h]);
                }
            }
            #pragma unroll
            for (int off = 32; off; off >>= 1){
                #pragma unroll
                for (int h = 0; h < 4; ++h){
                    sw[h]  += __shfl_down(sw[h],  off);
                    swx[h] += __shfl_down(swx[h], off);
                }
            }
            if (jl == 0){
                #pragma unroll
                for (int h = 0; h < 4; ++h) S_s[il][h] = swx[h] / sw[h];
            }
            __syncthreads();
            {
                int hc = tid & 63, row = tid >> 6;
                float v = S_s[row][hc >> 4] * p.g1_Wl[hc] + p.g1_b[hc];
                h_s[row][hc] = elu1(v);
            }
            __syncthreads();
            {
                int c = tid & 63, row = tid >> 6;
                float al = 0.f, ar = 0.f;
                #pragma unroll 8
                for (int k = 0; k < 64; ++k){
                    float hv = h_s[row][k];
                    al = fmaf(hv, Wl2s[k*64 + c], al);
                    ar = fmaf(hv, Wr2s[k*64 + c], ar);
                }
                size_t ridx = (size_t)(bt*NN + ig*32 + s*4 + row);
                p.xl2[ridx*HH + c] = al;
                p.xr2[ridx*HH + c] = ar;
                float a2 = p.g2_att[c];
                float pu = a2 * ar, pv = a2 * al;
                #pragma unroll
                for (int off = 32; off; off >>= 1){
                    pu += __shfl_down(pu, off);
                    pv += __shfl_down(pv, off);
                }
                if (c == 0){ p.ui[ridx] = pu; p.vj[ridx] = pv; }
            }
            __syncthreads();
        }
    }
    grid_barrier(p.bar);

    // ================= P2: GAT2 flash (32-row tile / block) =================
    {
        float (*xrT)[34] = (float(*)[34])smem;             // 8704
        float (*xlT)[68] = (float(*)[68])(smem + 8704);    // 17408
        float (*xlR)[68] = (float(*)[68])(smem + 26112);   // 17408
        float (*w_s)[68] = (float(*)[68])(smem + 43520);   // 8704
        float* Zl   = (float*)(smem + 52224);              // 128
        float* msum = (float*)(smem + 52352);              // 256
        int bt = blk >> 4, it = blk & 15;
        int i0 = it*32, t = bt % TT, base = bt*NN;
        const uchar* M = t ? p.M1 : p.M0;
        #pragma unroll
        for (int e = 0; e < 2; ++e){
            int idx = e*256 + tid;
            int r = idx >> 4, c4 = idx & 15;
            float4 v = *(const float4*)&p.xr2[(size_t)(base+i0+r)*HH + 4*c4];
            xrT[4*c4+0][r] = v.x; xrT[4*c4+1][r] = v.y;
            xrT[4*c4+2][r] = v.z; xrT[4*c4+3][r] = v.w;
        }
        if (tid < 32) Zl[tid] = 0.f;
        if (tid < 64) msum[tid] = 0.f;
        __syncthreads();
        int ti = tid >> 4, tj = tid & 15;
        int iL = ti*2, jL = tj*4;
        int ir = ti, tc = tj;
        float2 u2 = *(const float2*)&p.ui[base + i0 + iL];
        float4 accA0 = {0,0,0,0}, accA1 = {0,0,0,0};
        for (int jt = 0; jt < 8; ++jt){
            int j0 = jt*64;
            #pragma unroll
            for (int q = 0; q < 4; ++q){
                int idx = q*256 + tid;
                int r = idx >> 4, c4 = idx & 15;
                float4 v = *(const float4*)&p.xl2[(size_t)(base+j0+r)*HH + 4*c4];
                *(float4*)&xlR[r][4*c4] = v;
                xlT[4*c4+0][r] = v.x; xlT[4*c4+1][r] = v.y;
                xlT[4*c4+2][r] = v.z; xlT[4*c4+3][r] = v.w;
            }
            __syncthreads();
            float4 v4 = *(const float4*)&p.vj[base + j0 + jL];
            float e0[4], e1[4];
            e0[0] = 0.6f*(u2.x + v4.x); e0[1] = 0.6f*(u2.x + v4.y);
            e0[2] = 0.6f*(u2.x + v4.z); e0[3] = 0.6f*(u2.x + v4.w);
            e1[0] = 0.6f*(u2.y + v4.x); e1[1] = 0.6f*(u2.y + v4.y);
            e1[2] = 0.6f*(u2.y + v4.z); e1[3] = 0.6f*(u2.y + v4.w);
            #pragma unroll 8
            for (int c = 0; c < 64; ++c){
                float qa = 0.4f * p.g2_att[c];
                float2 a2 = *(const float2*)&xrT[c][iL];
                float4 b4 = *(const float4*)&xlT[c][jL];
                e0[0] = fmaf(qa, fabsf(a2.x + b4.x), e0[0]);
                e0[1] = fmaf(qa, fabsf(a2.x + b4.y), e0[1]);
                e0[2] = fmaf(qa, fabsf(a2.x + b4.z), e0[2]);
                e0[3] = fmaf(qa, fabsf(a2.x + b4.w), e0[3]);
                e1[0] = fmaf(qa, fabsf(a2.y + b4.x), e1[0]);
                e1[1] = fmaf(qa, fabsf(a2.y + b4.y), e1[1]);
                e1[2] = fmaf(qa, fabsf(a2.y + b4.z), e1[2]);
                e1[3] = fmaf(qa, fabsf(a2.y + b4.w), e1[3]);
            }
            uchar4 mr0 = *(const uchar4*)&M[(size_t)(i0+iL+0)*NN + j0 + jL];
            uchar4 mr1 = *(const uchar4*)&M[(size_t)(i0+iL+1)*NN + j0 + jL];
            float4 w0, w1;
            w0.x = mr0.x ? __expf(e0[0]) : 0.f;
            w0.y = mr0.y ? __expf(e0[1]) : 0.f;
            w0.z = mr0.z ? __expf(e0[2]) : 0.f;
            w0.w = mr0.w ? __expf(e0[3]) : 0.f;
            w1.x = mr1.x ? __expf(e1[0]) : 0.f;
            w1.y = mr1.y ? __expf(e1[1]) : 0.f;
            w1.z = mr1.z ? __expf(e1[2]) : 0.f;
            w1.w = mr1.w ? __expf(e1[3]) : 0.f;
            *(float4*)&w_s[iL+0][jL] = w0;
            *(float4*)&w_s[iL+1][jL] = w1;
            float zi0 = w0.x + w0.y + w0.z + w0.w;
            float zi1 = w1.x + w1.y + w1.z + w1.w;
            #pragma unroll
            for (int off = 8; off; off >>= 1){
                zi0 += __shfl_down(zi0, off);
                zi1 += __shfl_down(zi1, off);
            }
            if (tj == 0){
                atomicAdd(&Zl[iL+0], zi0);
                atomicAdd(&Zl[iL+1], zi1);
            }
            __syncthreads();
            #pragma unroll 4
            for (int j4 = 0; j4 < 16; ++j4){
                float4 wa = *(float4*)&w_s[ir][4*j4];
                float4 wb = *(float4*)&w_s[ir+16][4*j4];
                float4 x0 = *(float4*)&xlR[4*j4+0][4*tc];
                float4 x1 = *(float4*)&xlR[4*j4+1][4*tc];
                float4 x2 = *(float4*)&xlR[4*j4+2][4*tc];
                float4 x3 = *(float4*)&xlR[4*j4+3][4*tc];
                accA0.x += wa.x*x0.x + wa.y*x1.x + wa.z*x2.x + wa.w*x3.x;
                accA0.y += wa.x*x0.y + wa.y*x1.y + wa.z*x2.y + wa.w*x3.y;
                accA0.z += wa.x*x0.z + wa.y*x1.z + wa.z*x2.z + wa.w*x3.z;
                accA0.w += wa.x*x0.w + wa.y*x1.w + wa.z*x2.w + wa.w*x3.w;
                accA1.x += wb.x*x0.x + wb.y*x1.x + wb.z*x2.x + wb.w*x3.x;
                accA1.y += wb.x*x0.y + wb.y*x1.y + wb.z*x2.y + wb.w*x3.y;
                accA1.z += wb.x*x0.z + wb.y*x1.z + wb.z*x2.z + wb.w*x3.z;
                accA1.w += wb.x*x0.w + wb.y*x1.w + wb.z*x2.w + wb.w*x3.w;
            }
            __syncthreads();
        }
        float rz0 = 1.f / Zl[ir];
        float rz1 = 1.f / Zl[ir+16];
        float4 b4 = ((const float4*)p.g2_b)[tc];
        float4 h0, h1;
        h0.x = elu1(accA0.x*rz0 + b4.x); h0.y = elu1(accA0.y*rz0 + b4.y);
        h0.z = elu1(accA0.z*rz0 + b4.z); h0.w = elu1(accA0.w*rz0 + b4.w);
        h1.x = elu1(accA1.x*rz1 + b4.x); h1.y = elu1(accA1.y*rz1 + b4.y);
        h1.z = elu1(accA1.z*rz1 + b4.z); h1.w = elu1(accA1.w*rz1 + b4.w);
        atomicAdd(&msum[4*tc+0], h0.x + h1.x);
        atomicAdd(&msum[4*tc+1], h0.y + h1.y);
        atomicAdd(&msum[4*tc+2], h0.z + h1.z);
        atomicAdd(&msum[4*tc+3], h0.w + h1.w);
        __syncthreads();
        if (tid < 64) p.meanPart[(size_t)(bt*16 + it)*64 + tid] = msum[tid];
    }
    grid_barrier(p.bar);

    // ================= P3: tail — hseq, gi0, serial GRU x2, head =================
    if (blk != 0) return;
    {
        float* hseq_s = (float*)smem;                 // 4096 B
        float* gi_s   = (float*)(smem + 4096);        // 12288 B
        float* y_s    = (float*)(smem + 16384);       // 4096 B
        float (*sc_s)[TT]  = (float(*)[TT])(smem + 20480);
        float (*at_s)[TT]  = (float(*)[TT])(smem + 20480 + 64);
        float (*fin_s)[HH] = (float(*)[HH])(smem + 20480 + 128);
        float (*z_s)[HH]   = (float(*)[HH])(smem + 20480 + 128 + 512);
        float (*g_s)[HH]   = (float(*)[HH])(smem + 20480 + 128 + 1024);
        float* mu_s = (float*)(smem + 20480 + 128 + 1536);
        float* iv_s = (float*)(smem + 20480 + 128 + 1536 + 8);
        int wave = tid >> 6, lane = tid & 63;
        for (int o = tid; o < BB*TT*HH; o += 256){
            int bt = o >> 6, c = o & 63;
            float s = 0.f;
            #pragma unroll
            for (int itt = 0; itt < 16; ++itt)
                s += p.meanPart[(size_t)(bt*16 + itt)*64 + c];
            hseq_s[o] = s * (1.f/(float)NN);
        }
        __syncthreads();
        for (int o = tid; o < BB*TT*192; o += 256){
            int bt = o / 192, g = o % 192;
            float a = p.bih0[g];
            #pragma unroll 8
            for (int k = 0; k < HH; ++k)
                a = fmaf(hseq_s[bt*HH + k], p.Wih0[k*192 + g], a);
            gi_s[o] = a;
        }
        __syncthreads();
        if (wave < 2){
            int b = wave;
            const float4* WT = (const float4*)p.WT4;
            float y[TT], g1r[TT], g1z[TT], g1n[TT];
            {
                float bhr = p.bhh0[lane], bhz = p.bhh0[64+lane], bhn = p.bhh0[128+lane];
                float h = 0.f;
                for (int t = 0; t < TT; ++t){
                    float ghr = bhr, ghz = bhz, ghn = bhn;
                    #pragma unroll
                    for (int k = 0; k < 64; ++k){
                        float4 w4 = WT[lane*64 + k];
                        float hk = __shfl(h, k);
                        ghr = fmaf(w4.x, hk, ghr);
                        ghz = fmaf(w4.y, hk, ghz);
                        ghn = fmaf(w4.z, hk, ghn);
                    }
                    const float* gi = &gi_s[(b*TT + t)*192];
                    float r = sigm(gi[lane] + ghr);
                    float z = sigm(gi[64+lane] + ghz);
                    float n = tanhf(gi[128+lane] + r*ghn);
                    h = (1.f - z)*n + z*h;
                    y[t] = h;
                }
            }
            {
                float bi1r = p.bih1[lane], bi1z = p.bih1[64+lane], bi1n = p.bih1[128+lane];
                #pragma unroll
                for (int t = 0; t < TT; ++t){ g1r[t] = bi1r; g1z[t] = bi1z; g1n[t] = bi1n; }
                #pragma unroll 8
                for (int k = 0; k < 64; ++k){
                    float4 w4 = WT[4096 + lane*64 + k];
                    #pragma unroll
                    for (int t = 0; t < TT; ++t){
                        float yk = __shfl(y[t], k);
                        g1r[t] = fmaf(w4.x, yk, g1r[t]);
                        g1z[t] = fmaf(w4.y, yk, g1z[t]);
                        g1n[t] = fmaf(w4.z, yk, g1n[t]);
                    }
                }
            }
            {
                float bhr = p.bhh1[lane], bhz = p.bhh1[64+lane], bhn = p.bhh1[128+lane];
                float h = 0.f;
                for (int t = 0; t < TT; ++t){
                    float ghr = bhr, ghz = bhz, ghn = bhn;
                    #pragma unroll
                    for (int k = 0; k < 64; ++k){
                        float4 w4 = WT[2*4096 + lane*64 + k];
                        float hk = __shfl(h, k);
                        ghr = fmaf(w4.x, hk, ghr);
                        ghz = fmaf(w4.y, hk, ghz);
                        ghn = fmaf(w4.z, hk, ghn);
                    }
                    float r = sigm(g1r[t] + ghr);
                    float z = sigm(g1z[t] + ghz);
                    float n = tanhf(g1n[t] + r*ghn);
                    h = (1.f - z)*n + z*h;
                    y_s[(b*TT + t)*HH + lane] = h;
                }
            }
        }
        __syncthreads();
        if (tid < BB*TT){
            int bb = tid >> 3, t = tid & 7;
            float s = p.attnb[0];
            const float* r = &y_s[(bb*TT+t)*HH];
            for (int h = 0; h < HH; ++h) s += r[h]*p.attnW[h];
            sc_s[bb][t] = s;
        }
        __syncthreads();
        if (tid < BB){
            float mx = -INFINITY;
            for (int t = 0; t < TT; ++t) mx = fmaxf(mx, sc_s[tid][t]);
            float se = 0.f;
            for (int t = 0; t < TT; ++t){ float w = expf(sc_s[tid][t]-mx); at_s[tid][t] = w; se += w; }
            for (int t = 0; t < TT; ++t){
                at_s[tid][t] /= se;
                p.out[BB*NC + TT + tid*TT + t] = at_s[tid][t];
            }
        }
        __syncthreads();
        if (tid < BB*HH){
            int bb = tid >> 6, h = tid & 63;
            float a = 0.f;
            for (int t = 0; t < TT; ++t) a += at_s[bb][t]*y_s[(bb*TT+t)*HH + h];
            fin_s[bb][h] = a;
        }
        __syncthreads();
        if (tid < BB*HH){
            int bb = tid >> 6, h = tid & 63;
            float a = p.b1[h];
            for (int k = 0; k < HH; ++k) a += fin_s[bb][k]*p.W1[k*HH+h];
            z_s[bb][h] = a;
        }
        __syncthreads();
        if (tid < BB){
            float mu = 0.f;
            for (int h = 0; h < HH; ++h) mu += z_s[tid][h];
            mu *= (1.f/HH);
            float v = 0.f;
            for (int h = 0; h < HH; ++h){ float d = z_s[tid][h]-mu; v += d*d; }
            v *= (1.f/HH);
            mu_s[tid] = mu; iv_s[tid] = 1.f/sqrtf(v + 1e-5f);
        }
        __syncthreads();
        if (tid < BB*HH){
            int bb = tid >> 6, h = tid & 63;
            float zn = (z_s[bb][h]-mu_s[bb])*iv_s[bb]*p.lng[h] + p.lnb[h];
            g_s[bb][h] = 0.5f*zn*(1.f + erff(zn*0.70710678118654752f));
        }
        __syncthreads();
        if (tid < BB*NC){
            int bb = tid / NC, c = tid % NC;
            float a = p.b2[c];
            for (int k = 0; k < HH; ++k) a += g_s[bb][k]*p.W2[k*NC+c];
            p.out[bb*NC + c] = a;
        }
    }
}

extern "C" void kernel_launch(void* const* d_in, const int* in_sizes, int n_in,
                              void* d_out, int out_size, void* d_ws, size_t ws_size,
                              hipStream_t stream)
{
    Prm p;
    p.x_seq = (const float*)d_in[0];
    p.sadj  = (const float*)d_in[1];
    p.dW    = (const float*)d_in[2];
    p.lamp  = (const float*)d_in[3];
    p.g1_Wl = (const float*)d_in[4];
    p.g1_Wr = (const float*)d_in[5];
    p.g1_att= (const float*)d_in[6];
    p.g1_b  = (const float*)d_in[7];
    p.g2_Wl = (const float*)d_in[8];
    p.g2_Wr = (const float*)d_in[9];
    p.g2_att= (const float*)d_in[10];
    p.g2_b  = (const float*)d_in[11];
    p.Wih0  = (const float*)d_in[12];
    const float* Whh0 = (const float*)d_in[13];
    p.bih0  = (const float*)d_in[14];
    p.bhh0  = (const float*)d_in[15];
    const float* Wih1 = (const float*)d_in[16];
    const float* Whh1 = (const float*)d_in[17];
    p.bih1  = (const float*)d_in[18];
    p.bhh1  = (const float*)d_in[19];
    p.attnW = (const float*)d_in[20];
    p.attnb = (const float*)d_in[21];
    p.W1    = (const float*)d_in[22];
    p.b1    = (const float*)d_in[23];
    p.lng   = (const float*)d_in[24];
    p.lnb   = (const float*)d_in[25];
    p.W2    = (const float*)d_in[26];
    p.b2    = (const float*)d_in[27];
    p.out   = (float*)d_out;

    const int RWS = BB*TT*NN*HH;                  // 524288
    p.M0 = (uchar*)d_ws;                          // 262144 B
    p.M1 = p.M0 + (size_t)NN*NN;                  // 262144 B
    float* fb = (float*)(p.M1 + (size_t)NN*NN);
    p.WT4 = fb;                                   // 49152 floats
    p.xl2 = p.WT4 + 3*4096*4;                     // 524288
    p.xr2 = p.xl2 + RWS;                          // 524288
    p.ui  = p.xr2 + RWS;                          // 8192
    p.vj  = p.ui  + BB*TT*NN;                     // 8192
    p.meanPart = p.vj + BB*TT*NN;                 // 16384
    p.bar = (unsigned*)(p.meanPart + 16*16*64);   // 2 uints

    k_init<<<48, 256, 0, stream>>>(Whh0, Wih1, Whh1, p.lamp,
                                   (float4*)p.WT4, p.bar, p.out);
    mega  <<<NBLK, 256, 0, stream>>>(p);
}

// Round 8
// 232.990 us; speedup vs baseline: 1.6769x; 1.6769x over previous
//
#include <hip/hip_runtime.h>
#include <math.h>

#define BB 2
#define TT 8
#define NN 512
#define HH 64
#define NC 10

typedef unsigned char uchar;

__device__ __forceinline__ float elu1(float v){ return v > 0.f ? v : expm1f(v); }
__device__ __forceinline__ float sigm(float v){ return 1.f/(1.f+expf(-v)); }

// ---------------- K0: masks M0/M1; zero hseq; AB; GRU weight transposes --------
// z==0 (64 blocks): M0[i][j] = sadj>0 || i==j ; M1 = M0 || (dW+dW^T > 0)
// z==1 (64 blocks): WT4 quad-transposes of Whh0, Wih1, Whh1
__global__ __launch_bounds__(256) void k_mask(
    const float* __restrict__ dW, const float* __restrict__ sadj,
    uchar* __restrict__ M0, uchar* __restrict__ M1,
    float* __restrict__ hseq,
    const float* __restrict__ att1, const float* __restrict__ Wr1,
    const float* __restrict__ Wl1, float* __restrict__ AB,
    const float* __restrict__ Whh0, const float* __restrict__ Wih1,
    const float* __restrict__ Whh1, float4* __restrict__ WT4)
{
    __shared__ float tr[64][65];
    int bx = blockIdx.x, by = blockIdx.y;
    int tid = threadIdx.x;
    if (blockIdx.z == 1){
        int idx = (by*8 + bx)*256 + tid;           // 0..16383, need 12288
        if (idx < 3*4096){
            int m = idx >> 12, r = idx & 4095;
            int gg = r >> 6, k = r & 63;
            const float* W = (m == 0) ? Whh0 : (m == 1) ? Wih1 : Whh1;
            float4 o;
            o.x = W[k*192 + gg];
            o.y = W[k*192 + 64 + gg];
            o.z = W[k*192 + 128 + gg];
            o.w = 0.f;
            WT4[idx] = o;
        }
        return;
    }
    int i0 = by*64, j0 = bx*64;
    #pragma unroll
    for (int q = 0; q < 4; ++q){
        int r = (tid >> 4) + 16*q, c4 = tid & 15;
        float4 v = *(const float4*)&dW[(size_t)(j0+r)*NN + i0 + 4*c4];
        tr[r][4*c4+0] = v.x; tr[r][4*c4+1] = v.y;
        tr[r][4*c4+2] = v.z; tr[r][4*c4+3] = v.w;
    }
    __syncthreads();
    #pragma unroll
    for (int q = 0; q < 4; ++q){
        int row = (tid >> 4) + 16*q, c4 = tid & 15;
        int i = i0 + row, j = j0 + 4*c4;
        float4 d  = *(const float4*)&dW[(size_t)i*NN + j];
        float4 sa = *(const float4*)&sadj[(size_t)i*NN + j];
        uchar4 m0, m1;
        float dd0 = d.x + tr[4*c4+0][row];
        float dd1 = d.y + tr[4*c4+1][row];
        float dd2 = d.z + tr[4*c4+2][row];
        float dd3 = d.w + tr[4*c4+3][row];
        m0.x = (sa.x > 0.f) || (i == j+0);
        m0.y = (sa.y > 0.f) || (i == j+1);
        m0.z = (sa.z > 0.f) || (i == j+2);
        m0.w = (sa.w > 0.f) || (i == j+3);
        m1.x = m0.x || (dd0 > 0.f);
        m1.y = m0.y || (dd1 > 0.f);
        m1.z = m0.z || (dd2 > 0.f);
        m1.w = m0.w || (dd3 > 0.f);
        *(uchar4*)&M0[(size_t)i*NN + j] = m0;
        *(uchar4*)&M1[(size_t)i*NN + j] = m1;
    }
    int flat = (by*8 + bx)*256 + tid;
    if (flat < BB*TT*HH) hseq[flat] = 0.f;
    if (bx == 0 && by == 0 && tid < 8){
        int h = tid & 3;
        const float* W = (tid < 4) ? Wr1 : Wl1;
        float s = 0.f;
        for (int c = 0; c < 16; ++c) s += att1[h*16+c]*W[h*16+c];
        AB[tid] = s;   // [0..4)=Ar_h, [4..8)=Al_h
    }
}

// ---------------- K1: GAT1 fused with lin2 (h1 stays in LDS) -------------------
// block: 4 i-rows x 64 j-lanes (8 j each). grid: (NN/4, B*T)
__global__ __launch_bounds__(256) void k_gat1f(
    const float* __restrict__ x_seq, const uchar* __restrict__ M0,
    const uchar* __restrict__ M1,
    const float* __restrict__ Wl, const float* __restrict__ Wr,
    const float* __restrict__ att, const float* __restrict__ bias,
    const float* __restrict__ AB,
    const float* __restrict__ Wl2, const float* __restrict__ Wr2,
    const float* __restrict__ att2,
    float* __restrict__ xl2, float* __restrict__ xr2,
    float* __restrict__ ui, float* __restrict__ vj)
{
    __shared__ float x_s[NN];
    __shared__ float S_s[4][4];
    __shared__ float h_s[4][HH];
    __shared__ float Wl2_s[64*64];
    __shared__ float Wr2_s[64*64];
    int bt = blockIdx.y; int t = bt % TT;
    int i0 = blockIdx.x * 4;
    int tid = threadIdx.x;
    int il = tid >> 6, jl = tid & 63;
    int i = i0 + il;
    const uchar* M = t ? M1 : M0;
    ((float2*)x_s)[tid] = ((const float2*)(x_seq + bt*NN))[tid];
    #pragma unroll
    for (int q = 0; q < 4; ++q){
        int idx = q*256 + tid;
        ((float4*)Wl2_s)[idx] = ((const float4*)Wl2)[idx];
        ((float4*)Wr2_s)[idx] = ((const float4*)Wr2)[idx];
    }
    __syncthreads();
    float xi = x_s[i];
    const uchar* Mrow = M + (size_t)i*NN;
    float xj[8], msk[8];
    #pragma unroll
    for (int jj = 0; jj < 8; ++jj){
        int j = jj*64 + jl;
        xj[jj] = x_s[j];
        msk[jj] = Mrow[j] ? 1.f : 0.f;
    }
    float sw[4] = {0,0,0,0}, swx[4] = {0,0,0,0};
    for (int h = 0; h < 4; ++h){
        float acc[8] = {0,0,0,0,0,0,0,0};
        #pragma unroll
        for (int c = 0; c < 16; ++c){
            int hc = h*16 + c;
            float wl = Wl[hc];
            float q  = 0.4f * att[hc];
            float pr = xi * Wr[hc];
            #pragma unroll
            for (int jj = 0; jj < 8; ++jj){
                float s = fmaf(xj[jj], wl, pr);
                acc[jj] = fmaf(q, fabsf(s), acc[jj]);
            }
        }
        float lin = 0.6f * xi * AB[h];
        float al6 = 0.6f * AB[4+h];
        #pragma unroll
        for (int jj = 0; jj < 8; ++jj){
            float e = acc[jj] + fmaf(al6, xj[jj], lin);
            float w = msk[jj] * __expf(e);
            sw[h] += w;
            swx[h] = fmaf(w, xj[jj], swx[h]);
        }
    }
    #pragma unroll
    for (int off = 32; off; off >>= 1){
        #pragma unroll
        for (int h = 0; h < 4; ++h){
            sw[h]  += __shfl_down(sw[h],  off);
            swx[h] += __shfl_down(swx[h], off);
        }
    }
    if (jl == 0){
        #pragma unroll
        for (int h = 0; h < 4; ++h) S_s[il][h] = swx[h] / sw[h];
    }
    __syncthreads();
    {
        int hc = tid & 63, row = tid >> 6;
        float v = S_s[row][hc >> 4] * Wl[hc] + bias[hc];
        h_s[row][hc] = elu1(v);
    }
    __syncthreads();
    {
        int c = tid & 63, row = tid >> 6;
        float al = 0.f, ar = 0.f;
        #pragma unroll 8
        for (int k = 0; k < 64; ++k){
            float hv = h_s[row][k];
            al = fmaf(hv, Wl2_s[k*64 + c], al);
            ar = fmaf(hv, Wr2_s[k*64 + c], ar);
        }
        size_t ridx = (size_t)(bt*NN + i0 + row);
        xl2[ridx*HH + c] = al;
        xr2[ridx*HH + c] = ar;
        float a2 = att2[c];
        float pu = a2 * ar, pv = a2 * al;
        #pragma unroll
        for (int off = 32; off; off >>= 1){
            pu += __shfl_down(pu, off);
            pv += __shfl_down(pv, off);
        }
        if (c == 0){ ui[ridx] = pu; vj[ridx] = pv; }
    }
}

// ---------------- K2: GAT2 flash — e, exp, aggregate, mean in one pass ---------
// block: (bt, 16-row i-tile), 256 threads = 16 ti x 16 tj. grid (32, 16).
// j mapping: j = tj + 16*jq  (stride-16 -> conflict-free LDS with pitch 68)
__global__ __launch_bounds__(256) void k_flash2(
    const float* __restrict__ xl2, const float* __restrict__ xr2,
    const uchar* __restrict__ M0, const uchar* __restrict__ M1,
    const float* __restrict__ att, const float* __restrict__ bias,
    const float* __restrict__ ui, const float* __restrict__ vj,
    float* __restrict__ hseq)
{
    __shared__ float xrR[16][68];
    __shared__ float xlR[64][68];
    __shared__ float w_s[16][68];
    __shared__ float vj_s[64];
    __shared__ float Zl[16];
    __shared__ float msum[64];
    int bt = blockIdx.y, it = blockIdx.x;
    int i0 = it*16, t = bt % TT, base = bt*NN;
    const uchar* M = t ? M1 : M0;
    int tid = threadIdx.x;
    int ti = tid >> 4, tj = tid & 15;
    *(float4*)&xrR[ti][4*tj] = *(const float4*)&xr2[(size_t)(base+i0+ti)*HH + 4*tj];
    if (tid < 64) msum[tid] = 0.f;
    float u = ui[base + i0 + ti];
    float zacc = 0.f;
    float4 acc = {0,0,0,0};
    for (int jt = 0; jt < 8; ++jt){
        int j0 = jt*64;
        #pragma unroll
        for (int q = 0; q < 4; ++q){
            int idx = q*256 + tid;
            int r = idx >> 4, c4 = idx & 15;
            *(float4*)&xlR[r][4*c4] = *(const float4*)&xl2[(size_t)(base+j0+r)*HH + 4*c4];
        }
        if (tid < 64) vj_s[tid] = vj[base + j0 + tid];
        __syncthreads();
        float e[4];
        #pragma unroll
        for (int jq = 0; jq < 4; ++jq)
            e[jq] = 0.6f*(u + vj_s[tj + 16*jq]);
        #pragma unroll 4
        for (int cq = 0; cq < 16; ++cq){
            float4 qa = ((const float4*)att)[cq];        // uniform -> s_load
            qa.x *= 0.4f; qa.y *= 0.4f; qa.z *= 0.4f; qa.w *= 0.4f;
            float4 a4 = *(const float4*)&xrR[ti][4*cq];  // broadcast
            #pragma unroll
            for (int jq = 0; jq < 4; ++jq){
                float4 b4 = *(const float4*)&xlR[tj + 16*jq][4*cq];
                e[jq] = fmaf(qa.x, fabsf(a4.x + b4.x), e[jq]);
                e[jq] = fmaf(qa.y, fabsf(a4.y + b4.y), e[jq]);
                e[jq] = fmaf(qa.z, fabsf(a4.z + b4.z), e[jq]);
                e[jq] = fmaf(qa.w, fabsf(a4.w + b4.w), e[jq]);
            }
        }
        const uchar* Mrow = M + (size_t)(i0+ti)*NN + j0;
        float zp = 0.f;
        #pragma unroll
        for (int jq = 0; jq < 4; ++jq){
            float w = Mrow[tj + 16*jq] ? __expf(e[jq]) : 0.f;
            w_s[ti][tj + 16*jq] = w;
            zp += w;
        }
        zp += __shfl_down(zp, 8);
        zp += __shfl_down(zp, 4);
        zp += __shfl_down(zp, 2);
        zp += __shfl_down(zp, 1);
        if (tj == 0) zacc += zp;
        __syncthreads();
        // aggregation: thread (ti, tc=tj) -> row ti, cols 4tj..4tj+3
        #pragma unroll 8
        for (int j = 0; j < 64; ++j){
            float w = w_s[ti][j];                         // broadcast
            float4 x4 = *(const float4*)&xlR[j][4*tj];
            acc.x = fmaf(w, x4.x, acc.x);
            acc.y = fmaf(w, x4.y, acc.y);
            acc.z = fmaf(w, x4.z, acc.z);
            acc.w = fmaf(w, x4.w, acc.w);
        }
        __syncthreads();
    }
    if (tj == 0) Zl[ti] = zacc;
    __syncthreads();
    float rz = 1.f / Zl[ti];
    float4 b4 = ((const float4*)bias)[tj];
    float4 h;
    h.x = elu1(acc.x*rz + b4.x);
    h.y = elu1(acc.y*rz + b4.y);
    h.z = elu1(acc.z*rz + b4.z);
    h.w = elu1(acc.w*rz + b4.w);
    atomicAdd(&msum[4*tj+0], h.x);
    atomicAdd(&msum[4*tj+1], h.y);
    atomicAdd(&msum[4*tj+2], h.z);
    atomicAdd(&msum[4*tj+3], h.w);
    __syncthreads();
    if (tid < 64) atomicAdd(&hseq[bt*HH + tid], msum[tid]*(1.f/(float)NN));
}

// ---------------- K3: serial GRU x2 (wave-per-batch, reg-resident) + head ------
// gi0 GEMV fused into the parallel prologue (was k_pre).
#define P4 65
__global__ __launch_bounds__(512) void k_gru2(
    const float* __restrict__ hseq, const float* __restrict__ Wih0,
    const float* __restrict__ bih0, const float4* __restrict__ WT4,
    const float* __restrict__ bhh0,
    const float* __restrict__ bih1, const float* __restrict__ bhh1,
    const float* __restrict__ lamp, const float* __restrict__ attn_W,
    const float* __restrict__ attn_b, const float* __restrict__ W1,
    const float* __restrict__ b1, const float* __restrict__ ln_g,
    const float* __restrict__ ln_b, const float* __restrict__ W2,
    const float* __restrict__ b2, float* __restrict__ out)
{
    __shared__ float4 WA[64*P4];          // 66560 B  (Whh of current layer)
    __shared__ float4 WB[64*P4];          // 66560 B  (Wih1)
    __shared__ float gi_s[BB*TT*192];     // 12288 B
    __shared__ float hs[BB*TT*HH];        // 4096 B
    __shared__ float y_s[BB*TT*HH];       // 4096 B
    __shared__ float sc_s[BB][TT], at_s[BB][TT];
    __shared__ float fin_s[BB][HH], z_s[BB][HH], g_s[BB][HH];
    __shared__ float mu_s[BB], iv_s[BB];
    int tid = threadIdx.x;
    int wave = tid >> 6, lane = tid & 63;
    for (int v = tid; v < 4096; v += 512){
        WA[(v >> 6)*P4 + (v & 63)] = WT4[v];          // m=0: Whh0
        WB[(v >> 6)*P4 + (v & 63)] = WT4[4096 + v];   // m=1: Wih1
    }
    for (int v = tid; v < BB*TT*HH; v += 512) hs[v] = hseq[v];
    __syncthreads();
    for (int o = tid; o < BB*TT*192; o += 512){       // gi0 GEMV (was k_pre)
        int bt = o / 192, g = o % 192;
        float a = bih0[g];
        #pragma unroll 8
        for (int k = 0; k < HH; ++k)
            a = fmaf(hs[bt*HH + k], Wih0[k*192 + g], a);
        gi_s[o] = a;
    }
    __syncthreads();
    if (wave < 2){
        int b = wave;
        float y[TT], g1r[TT], g1z[TT], g1n[TT];
        {
            float bhr = bhh0[lane], bhz = bhh0[64+lane], bhn = bhh0[128+lane];
            float h = 0.f;
            for (int t = 0; t < TT; ++t){
                float ghr = bhr, ghz = bhz, ghn = bhn;
                #pragma unroll 16
                for (int k = 0; k < 64; ++k){
                    float4 w4 = WA[lane*P4 + k];
                    float hk = __shfl(h, k);
                    ghr = fmaf(w4.x, hk, ghr);
                    ghz = fmaf(w4.y, hk, ghz);
                    ghn = fmaf(w4.z, hk, ghn);
                }
                const float* gi = &gi_s[(b*TT + t)*192];
                float r = sigm(gi[lane] + ghr);
                float z = sigm(gi[64+lane] + ghz);
                float n = tanhf(gi[128+lane] + r*ghn);
                h = (1.f - z)*n + z*h;
                y[t] = h;
            }
        }
        {
            float bi1r = bih1[lane], bi1z = bih1[64+lane], bi1n = bih1[128+lane];
            #pragma unroll
            for (int t = 0; t < TT; ++t){ g1r[t] = bi1r; g1z[t] = bi1z; g1n[t] = bi1n; }
            #pragma unroll 8
            for (int k = 0; k < 64; ++k){
                float4 w4 = WB[lane*P4 + k];
                #pragma unroll
                for (int t = 0; t < TT; ++t){
                    float yk = __shfl(y[t], k);
                    g1r[t] = fmaf(w4.x, yk, g1r[t]);
                    g1z[t] = fmaf(w4.y, yk, g1z[t]);
                    g1n[t] = fmaf(w4.z, yk, g1n[t]);
                }
            }
        }
        __syncthreads();
        // (waves 2..7 hit the same barrier below)
        {
            float bhr = bhh1[lane], bhz = bhh1[64+lane], bhn = bhh1[128+lane];
            float h = 0.f;
            for (int t = 0; t < TT; ++t){
                float ghr = bhr, ghz = bhz, ghn = bhn;
                #pragma unroll 16
                for (int k = 0; k < 64; ++k){
                    float4 w4 = WB[lane*P4 + k];      // WB re-staged? no — see below
                    float hk = __shfl(h, k);
                    ghr = fmaf(w4.x, hk, ghr);
                    ghz = fmaf(w4.y, hk, ghz);
                    ghn = fmaf(w4.z, hk, ghn);
                }
                float r = sigm(g1r[t] + ghr);
                float z = sigm(g1z[t] + ghz);
                float n = tanhf(g1n[t] + r*ghn);
                h = (1.f - z)*n + z*h;
                y_s[(b*TT + t)*HH + lane] = h;
            }
        }
    } else {
        __syncthreads();
    }
    __syncthreads();
    // NOTE: between the two barriers above, waves 2..7 restage WB <- Whh1
    // Implemented here (after first sync, before waves 0-1 read WB for layer1):
    // -- this ordering is enforced by the barrier pair in both branches.
    // (restage code lives in the else-branch region below for waves>=2)
    // ---- head ----
    float lam = fmaxf(lamp[0], 0.01f);
    if (tid < TT) out[BB*NC + tid] = expf(-lam*(float)tid);
    if (tid < BB*TT){
        int bb = tid >> 3, t = tid & 7;
        float s = attn_b[0];
        const float* r = &y_s[(bb*TT+t)*HH];
        for (int h = 0; h < HH; ++h) s += r[h]*attn_W[h];
        sc_s[bb][t] = s;
    }
    __syncthreads();
    if (tid < BB){
        float mx = -INFINITY;
        for (int t = 0; t < TT; ++t) mx = fmaxf(mx, sc_s[tid][t]);
        float se = 0.f;
        for (int t = 0; t < TT; ++t){ float w = expf(sc_s[tid][t]-mx); at_s[tid][t] = w; se += w; }
        for (int t = 0; t < TT; ++t){
            at_s[tid][t] /= se;
            out[BB*NC + TT + tid*TT + t] = at_s[tid][t];
        }
    }
    __syncthreads();
    if (tid < BB*HH){
        int bb = tid >> 6, h = tid & 63;
        float a = 0.f;
        for (int t = 0; t < TT; ++t) a += at_s[bb][t]*y_s[(bb*TT+t)*HH + h];
        fin_s[bb][h] = a;
    }
    __syncthreads();
    if (tid < BB*HH){
        int bb = tid >> 6, h = tid & 63;
        float a = b1[h];
        for (int k = 0; k < HH; ++k) a += fin_s[bb][k]*W1[k*HH+h];
        z_s[bb][h] = a;
    }
    __syncthreads();
    if (tid < BB){
        float mu = 0.f;
        for (int h = 0; h < HH; ++h) mu += z_s[tid][h];
        mu *= (1.f/HH);
        float v = 0.f;
        for (int h = 0; h < HH; ++h){ float d = z_s[tid][h]-mu; v += d*d; }
        v *= (1.f/HH);
        mu_s[tid] = mu; iv_s[tid] = 1.f/sqrtf(v + 1e-5f);
    }
    __syncthreads();
    if (tid < BB*HH){
        int bb = tid >> 6, h = tid & 63;
        float zn = (z_s[bb][h]-mu_s[bb])*iv_s[bb]*ln_g[h] + ln_b[h];
        g_s[bb][h] = 0.5f*zn*(1.f + erff(zn*0.70710678118654752f));
    }
    __syncthreads();
    if (tid < BB*NC){
        int bb = tid / NC, c = tid % NC;
        float a = b2[c];
        for (int k = 0; k < HH; ++k) a += g_s[bb][k]*W2[k*NC+c];
        out[bb*NC + c] = a;
    }
}

// Restage helper removed: instead of re-staging WB with Whh1 between barriers
// (divergent-barrier hazard), layer-1 Whh is read from WA2 = a third LDS copy.
// But LDS budget forbids a third 66KB buffer — so we pre-merge:
// WT4 layout already holds Whh1 at offset 2*4096; layer-1 loop reads WB after
// waves>=2 restage it. The barrier pair above makes this safe:
//   barrier1: waves0-1 done reading WB(Wih1); waves>=2 arrive
//   [waves>=2 would restage here — but they can't re-enter the if-branch]
// To keep control flow non-divergent around barriers, we instead pre-stage
// WB with Whh1 *before* the serial section even starts? Not possible (Wih1
// needed first). Resolution implemented above: layer-1 reads WB which is
// re-staged by ALL 512 threads between the two __syncthreads() calls — see
// fixed code below (this comment documents the hazard analysis).

extern "C" void kernel_launch(void* const* d_in, const int* in_sizes, int n_in,
                              void* d_out, int out_size, void* d_ws, size_t ws_size,
                              hipStream_t stream);

// ---- corrected k_gru2 with non-divergent WB restage ----
__global__ __launch_bounds__(512) void k_gru2b(
    const float* __restrict__ hseq, const float* __restrict__ Wih0,
    const float* __restrict__ bih0, const float4* __restrict__ WT4,
    const float* __restrict__ bhh0,
    const float* __restrict__ bih1, const float* __restrict__ bhh1,
    const float* __restrict__ lamp, const float* __restrict__ attn_W,
    const float* __restrict__ attn_b, const float* __restrict__ W1,
    const float* __restrict__ b1, const float* __restrict__ ln_g,
    const float* __restrict__ ln_b, const float* __restrict__ W2,
    const float* __restrict__ b2, float* __restrict__ out)
{
    __shared__ float4 WA[64*P4];
    __shared__ float4 WB[64*P4];
    __shared__ float gi_s[BB*TT*192];
    __shared__ float hs[BB*TT*HH];
    __shared__ float y_s[BB*TT*HH];
    __shared__ float sc_s[BB][TT], at_s[BB][TT];
    __shared__ float fin_s[BB][HH], z_s[BB][HH], g_s[BB][HH];
    __shared__ float mu_s[BB], iv_s[BB];
    int tid = threadIdx.x;
    int wave = tid >> 6, lane = tid & 63;
    for (int v = tid; v < 4096; v += 512){
        WA[(v >> 6)*P4 + (v & 63)] = WT4[v];          // Whh0
        WB[(v >> 6)*P4 + (v & 63)] = WT4[4096 + v];   // Wih1
    }
    for (int v = tid; v < BB*TT*HH; v += 512) hs[v] = hseq[v];
    __syncthreads();
    for (int o = tid; o < BB*TT*192; o += 512){
        int bt = o / 192, g = o % 192;
        float a = bih0[g];
        #pragma unroll 8
        for (int k = 0; k < HH; ++k)
            a = fmaf(hs[bt*HH + k], Wih0[k*192 + g], a);
        gi_s[o] = a;
    }
    __syncthreads();
    float y[TT], g1r[TT], g1z[TT], g1n[TT];
    if (wave < 2){
        int b = wave;
        float bhr = bhh0[lane], bhz = bhh0[64+lane], bhn = bhh0[128+lane];
        float h = 0.f;
        for (int t = 0; t < TT; ++t){
            float ghr = bhr, ghz = bhz, ghn = bhn;
            #pragma unroll 16
            for (int k = 0; k < 64; ++k){
                float4 w4 = WA[lane*P4 + k];
                float hk = __shfl(h, k);
                ghr = fmaf(w4.x, hk, ghr);
                ghz = fmaf(w4.y, hk, ghz);
                ghn = fmaf(w4.z, hk, ghn);
            }
            const float* gi = &gi_s[(b*TT + t)*192];
            float r = sigm(gi[lane] + ghr);
            float z = sigm(gi[64+lane] + ghz);
            float n = tanhf(gi[128+lane] + r*ghn);
            h = (1.f - z)*n + z*h;
            y[t] = h;
        }
        float bi1r = bih1[lane], bi1z = bih1[64+lane], bi1n = bih1[128+lane];
        #pragma unroll
        for (int t = 0; t < TT; ++t){ g1r[t] = bi1r; g1z[t] = bi1z; g1n[t] = bi1n; }
        #pragma unroll 8
        for (int k = 0; k < 64; ++k){
            float4 w4 = WB[lane*P4 + k];
            #pragma unroll
            for (int t = 0; t < TT; ++t){
                float yk = __shfl(y[t], k);
                g1r[t] = fmaf(w4.x, yk, g1r[t]);
                g1z[t] = fmaf(w4.y, yk, g1z[t]);
                g1n[t] = fmaf(w4.z, yk, g1n[t]);
            }
        }
    }
    __syncthreads();   // all waves: waves0-1 done with WA(Whh0); restage WA <- Whh1
    for (int v = tid; v < 4096; v += 512)
        WA[(v >> 6)*P4 + (v & 63)] = WT4[2*4096 + v];  // Whh1
    __syncthreads();
    if (wave < 2){
        int b = wave;
        float bhr = bhh1[lane], bhz = bhh1[64+lane], bhn = bhh1[128+lane];
        float h = 0.f;
        for (int t = 0; t < TT; ++t){
            float ghr = bhr, ghz = bhz, ghn = bhn;
            #pragma unroll 16
            for (int k = 0; k < 64; ++k){
                float4 w4 = WA[lane*P4 + k];
                float hk = __shfl(h, k);
                ghr = fmaf(w4.x, hk, ghr);
                ghz = fmaf(w4.y, hk, ghz);
                ghn = fmaf(w4.z, hk, ghn);
            }
            float r = sigm(g1r[t] + ghr);
            float z = sigm(g1z[t] + ghz);
            float n = tanhf(g1n[t] + r*ghn);
            h = (1.f - z)*n + z*h;
            y_s[(b*TT + t)*HH + lane] = h;
        }
    }
    __syncthreads();
    float lam = fmaxf(lamp[0], 0.01f);
    if (tid < TT) out[BB*NC + tid] = expf(-lam*(float)tid);
    if (tid < BB*TT){
        int bb = tid >> 3, t = tid & 7;
        float s = attn_b[0];
        const float* r = &y_s[(bb*TT+t)*HH];
        for (int h = 0; h < HH; ++h) s += r[h]*attn_W[h];
        sc_s[bb][t] = s;
    }
    __syncthreads();
    if (tid < BB){
        float mx = -INFINITY;
        for (int t = 0; t < TT; ++t) mx = fmaxf(mx, sc_s[tid][t]);
        float se = 0.f;
        for (int t = 0; t < TT; ++t){ float w = expf(sc_s[tid][t]-mx); at_s[tid][t] = w; se += w; }
        for (int t = 0; t < TT; ++t){
            at_s[tid][t] /= se;
            out[BB*NC + TT + tid*TT + t] = at_s[tid][t];
        }
    }
    __syncthreads();
    if (tid < BB*HH){
        int bb = tid >> 6, h = tid & 63;
        float a = 0.f;
        for (int t = 0; t < TT; ++t) a += at_s[bb][t]*y_s[(bb*TT+t)*HH + h];
        fin_s[bb][h] = a;
    }
    __syncthreads();
    if (tid < BB*HH){
        int bb = tid >> 6, h = tid & 63;
        float a = b1[h];
        for (int k = 0; k < HH; ++k) a += fin_s[bb][k]*W1[k*HH+h];
        z_s[bb][h] = a;
    }
    __syncthreads();
    if (tid < BB){
        float mu = 0.f;
        for (int h = 0; h < HH; ++h) mu += z_s[tid][h];
        mu *= (1.f/HH);
        float v = 0.f;
        for (int h = 0; h < HH; ++h){ float d = z_s[tid][h]-mu; v += d*d; }
        v *= (1.f/HH);
        mu_s[tid] = mu; iv_s[tid] = 1.f/sqrtf(v + 1e-5f);
    }
    __syncthreads();
    if (tid < BB*HH){
        int bb = tid >> 6, h = tid & 63;
        float zn = (z_s[bb][h]-mu_s[bb])*iv_s[bb]*ln_g[h] + ln_b[h];
        g_s[bb][h] = 0.5f*zn*(1.f + erff(zn*0.70710678118654752f));
    }
    __syncthreads();
    if (tid < BB*NC){
        int bb = tid / NC, c = tid % NC;
        float a = b2[c];
        for (int k = 0; k < HH; ++k) a += g_s[bb][k]*W2[k*NC+c];
        out[bb*NC + c] = a;
    }
}

extern "C" void kernel_launch(void* const* d_in, const int* in_sizes, int n_in,
                              void* d_out, int out_size, void* d_ws, size_t ws_size,
                              hipStream_t stream)
{
    const float* x_seq = (const float*)d_in[0];
    const float* sadj  = (const float*)d_in[1];
    const float* dynW  = (const float*)d_in[2];
    const float* lamp  = (const float*)d_in[3];
    const float* g1_Wl = (const float*)d_in[4];
    const float* g1_Wr = (const float*)d_in[5];
    const float* g1_att= (const float*)d_in[6];
    const float* g1_b  = (const float*)d_in[7];
    const float* g2_Wl = (const float*)d_in[8];
    const float* g2_Wr = (const float*)d_in[9];
    const float* g2_att= (const float*)d_in[10];
    const float* g2_b  = (const float*)d_in[11];
    const float* Wih0  = (const float*)d_in[12];
    const float* Whh0  = (const float*)d_in[13];
    const float* bih0  = (const float*)d_in[14];
    const float* bhh0  = (const float*)d_in[15];
    const float* Wih1  = (const float*)d_in[16];
    const float* Whh1  = (const float*)d_in[17];
    const float* bih1  = (const float*)d_in[18];
    const float* bhh1  = (const float*)d_in[19];
    const float* attnW = (const float*)d_in[20];
    const float* attnb = (const float*)d_in[21];
    const float* W1    = (const float*)d_in[22];
    const float* b1    = (const float*)d_in[23];
    const float* lng   = (const float*)d_in[24];
    const float* lnb   = (const float*)d_in[25];
    const float* W2    = (const float*)d_in[26];
    const float* b2    = (const float*)d_in[27];
    float* out = (float*)d_out;

    const int RWS = BB*TT*NN*HH;              // 524288
    uchar* M0 = (uchar*)d_ws;                 // 262144 B
    uchar* M1 = M0 + (size_t)NN*NN;           // 262144 B
    float* fb = (float*)(M1 + (size_t)NN*NN);
    float* AB   = fb;                         // 16
    float* ui   = AB   + 16;                  // 8192
    float* vj   = ui   + BB*TT*NN;            // 8192
    float* xl2  = vj   + BB*TT*NN;            // 524288
    float* xr2  = xl2  + RWS;                 // 524288
    float* hseq = xr2  + RWS;                 // 1024
    float* WT4  = hseq + BB*TT*HH;            // 49152 floats
    // total ~5 MB

    k_mask  <<<dim3(8,8,2), 256, 0, stream>>>(dynW, sadj, M0, M1, hseq, g1_att, g1_Wr, g1_Wl, AB,
                                              Whh0, Wih1, Whh1, (float4*)WT4);
    k_gat1f <<<dim3(NN/4, BB*TT), 256, 0, stream>>>(x_seq, M0, M1, g1_Wl, g1_Wr, g1_att, g1_b, AB,
                                                    g2_Wl, g2_Wr, g2_att, xl2, xr2, ui, vj);
    k_flash2<<<dim3(NN/16, BB*TT), 256, 0, stream>>>(xl2, xr2, M0, M1, g2_att, g2_b, ui, vj, hseq);
    k_gru2b <<<1, 512, 0, stream>>>(hseq, Wih0, bih0, (const float4*)WT4, bhh0, bih1, bhh1,
                                    lamp, attnW, attnb, W1, b1, lng, lnb, W2, b2, out);
}